// Round 3
// baseline (535.987 us; speedup 1.0000x reference)
//
#include <hip/hip_runtime.h>

#define TOKENS 65536
#define DIM 64
#define NCODE 1024
#define MARGIN 2.5e-4f

#define OUT_IDX_OFF ((size_t)TOKENS * DIM)          // 4194304
#define OUT_LOSS_OFF (OUT_IDX_OFF + TOKENS)         // 4259840

// ws layout:
// [0,8)            double loss_sum
// [8,12)           uint   flag_count
// [16,16+4096)     float  bnorm[1024]
// [4112, ...)      int    flag_list[]

// ---------------------------------------------------------------------------
// numpy-bitwise f32 kernels — VERIFIED absmax=0 in round 2. Do not touch.
// ---------------------------------------------------------------------------
__device__ __forceinline__ float np_sumsq64(const float* __restrict__ x) {
#pragma clang fp contract(off)
    float r[8];
#pragma unroll
    for (int j = 0; j < 8; ++j) r[j] = x[j] * x[j];
#pragma unroll
    for (int i = 8; i < 64; i += 8) {
#pragma unroll
        for (int j = 0; j < 8; ++j) {
            float sq = x[i + j] * x[i + j];
            r[j] = r[j] + sq;
        }
    }
    return ((r[0] + r[1]) + (r[2] + r[3])) + ((r[4] + r[5]) + (r[6] + r[7]));
}

__device__ __forceinline__ float np_dot64(const float* __restrict__ a,
                                          const float* __restrict__ b) {
#pragma clang fp contract(off)
    float l[16];
#pragma unroll
    for (int j = 0; j < 16; ++j) {
        float acc = a[48 + j] * b[48 + j];
        acc = __fmaf_rn(a[32 + j], b[32 + j], acc);
        acc = __fmaf_rn(a[16 + j], b[16 + j], acc);
        acc = __fmaf_rn(a[j],      b[j],      acc);
        l[j] = acc;
    }
#pragma unroll
    for (int j = 0; j < 8; ++j) l[j] = l[j] + l[j + 8];
#pragma unroll
    for (int j = 0; j < 4; ++j) l[j] = l[j] + l[j + 4];
    l[0] = l[0] + l[2];
    l[1] = l[1] + l[3];
    return l[0] + l[1];
}

__global__ __launch_bounds__(256) void vq_bnorm(const float* __restrict__ cb,
                                                float* __restrict__ bnorm) {
    int k = blockIdx.x * 256 + threadIdx.x;
    bnorm[k] = np_sumsq64(cb + (size_t)k * DIM);
}

// ---------------------------------------------------------------------------
// Pass A: fast screen. Block = 256 threads = 4 waves; block owns 64 tokens.
// Wave w handles ALL 64 tokens (one per lane) x code quarter [w*256,(w+1)*256).
// Code row address is wave-uniform -> scalar s_load path, zero LDS-pipe use.
// Tokens whose top-2 gap < MARGIN are flagged for the exact-np pass.
// ---------------------------------------------------------------------------
__global__ __launch_bounds__(256, 4) void vq_fast(
    const float* __restrict__ z, const float* __restrict__ cb,
    const float* __restrict__ bnorm, float* __restrict__ out,
    unsigned int* __restrict__ flag_count, int* __restrict__ flag_list,
    double* __restrict__ loss_sum, unsigned int flag_cap) {
    __shared__ float lm1[4][64];
    __shared__ float lm2[4][64];
    __shared__ int   lbest[4][64];
    __shared__ int   s_best[64];
    __shared__ int   s_flag[64];

    const int tid = threadIdx.x;
    const int lane = tid & 63;
    // readfirstlane: make the wave id provably uniform so cb[k*64+j] becomes s_load
    const int w = __builtin_amdgcn_readfirstlane(tid >> 6);
    const int tbase = blockIdx.x * 64;
    const int t = tbase + lane;

    // token vector in registers
    float zr[DIM];
    {
        const float4* z4 = (const float4*)(z + (size_t)t * DIM);
#pragma unroll
        for (int j = 0; j < 16; ++j) {
            float4 v = z4[j];
            zr[4 * j + 0] = v.x; zr[4 * j + 1] = v.y;
            zr[4 * j + 2] = v.z; zr[4 * j + 3] = v.w;
        }
    }

    // ||z||^2 in f64, rounded once -> within 0.5 ulp(64) of exact
    double szd = 0.0;
#pragma unroll
    for (int j = 0; j < DIM; ++j) szd = fma((double)zr[j], (double)zr[j], szd);
    const float s_z = (float)szd;

    float m1 = 3.0e38f, m2 = 3.0e38f;
    int best = 0;
    const int kbase = w * 256;

    for (int kk = 0; kk < 256; ++kk) {
        const int k = kbase + kk;
        const float* __restrict__ crow = cb + (size_t)k * DIM;  // uniform addr
        float a0 = 0.f, a1 = 0.f, a2 = 0.f, a3 = 0.f;
#pragma unroll
        for (int j = 0; j < 16; ++j) {
            a0 = __fmaf_rn(zr[4 * j + 0], crow[4 * j + 0], a0);
            a1 = __fmaf_rn(zr[4 * j + 1], crow[4 * j + 1], a1);
            a2 = __fmaf_rn(zr[4 * j + 2], crow[4 * j + 2], a2);
            a3 = __fmaf_rn(zr[4 * j + 3], crow[4 * j + 3], a3);
        }
        float e = (a0 + a1) + (a2 + a3);
        float dd = __fmaf_rn(-2.0f, e, s_z + bnorm[k]);
        if (dd < m1)      { m2 = m1; m1 = dd; best = k; }
        else if (dd < m2) { m2 = dd; }
    }

    lm1[w][lane] = m1; lm2[w][lane] = m2; lbest[w][lane] = best;
    __syncthreads();

    // merge the 4 quarters' top-2 per token; flag near-ties
    if (tid < 64) {
        float M1 = lm1[0][tid], M2 = lm2[0][tid];
        int B = lbest[0][tid];
#pragma unroll
        for (int q = 1; q < 4; ++q) {
            float q1 = lm1[q][tid], q2 = lm2[q][tid];
            if (q1 < M1) { M2 = fminf(M1, q2); M1 = q1; B = lbest[q][tid]; }
            else         { M2 = fminf(M2, q1); }
        }
        int fl = (M2 - M1) < MARGIN;
        if (fl) {
            unsigned int pos = atomicAdd(flag_count, 1u);
            if (pos >= flag_cap) fl = 0;          // overflow: keep fast answer
            else flag_list[pos] = tbase + tid;
        }
        s_best[tid] = B;
        s_flag[tid] = fl;
    }
    __syncthreads();

    // epilogue: 4 threads per token, 16 floats each; flagged tokens deferred
    const int et = tid >> 2, eq = tid & 3;
    float loss_t = 0.0f;
    if (!s_flag[et]) {
        const int B = s_best[et];
        const float4* cq  = (const float4*)(cb + (size_t)B * DIM + eq * 16);
        const float4* zq4 = (const float4*)(z + (size_t)(tbase + et) * DIM + eq * 16);
        float4* o4 = (float4*)(out + (size_t)(tbase + et) * DIM + eq * 16);
#pragma unroll
        for (int jj = 0; jj < 4; ++jj) {
#pragma clang fp contract(off)
            float4 c = cq[jj];
            float4 zz = zq4[jj];
            float d0 = c.x - zz.x, d1 = c.y - zz.y;
            float d2 = c.z - zz.z, d3 = c.w - zz.w;
            float4 o;
            o.x = zz.x + d0; o.y = zz.y + d1;
            o.z = zz.z + d2; o.w = zz.w + d3;
            o4[jj] = o;
            loss_t = __fmaf_rn(d0, d0, loss_t);
            loss_t = __fmaf_rn(d1, d1, loss_t);
            loss_t = __fmaf_rn(d2, d2, loss_t);
            loss_t = __fmaf_rn(d3, d3, loss_t);
        }
        if (eq == 0) out[OUT_IDX_OFF + tbase + et] = (float)B;
    }
#pragma unroll
    for (int off = 32; off > 0; off >>= 1)
        loss_t += __shfl_down(loss_t, off);
    if (lane == 0) atomicAdd(loss_sum, (double)loss_t);
}

// ---------------------------------------------------------------------------
// Pass B: exact numpy-bitwise argmin for flagged tokens. One wave per token,
// lane l evaluates codes [l*16, l*16+16). Reuses round-2-verified np_* fns.
// ---------------------------------------------------------------------------
__global__ __launch_bounds__(256) void vq_exact(
    const float* __restrict__ z, const float* __restrict__ cb,
    const float* __restrict__ bnorm, float* __restrict__ out,
    const unsigned int* __restrict__ flag_count,
    const int* __restrict__ flag_list, double* __restrict__ loss_sum,
    unsigned int flag_cap) {
    const int wave = threadIdx.x >> 6;
    const int lane = threadIdx.x & 63;
    unsigned int count = *flag_count;
    if (count > flag_cap) count = flag_cap;
    const unsigned int gw = blockIdx.x * 4 + wave;
    const unsigned int NW = gridDim.x * 4;

    for (unsigned int li = gw; li < count; li += NW) {
        const int t = flag_list[li];
        float zr[DIM];
        {
            const float4* z4 = (const float4*)(z + (size_t)t * DIM);
#pragma unroll
            for (int j = 0; j < 16; ++j) {
                float4 v = z4[j];
                zr[4 * j + 0] = v.x; zr[4 * j + 1] = v.y;
                zr[4 * j + 2] = v.z; zr[4 * j + 3] = v.w;
            }
        }
        const float s_z = np_sumsq64(zr);

        float m1 = 3.0e38f;
        int best = NCODE;
        for (int c = 0; c < 16; ++c) {
            const int k = lane * 16 + c;
            float cr[DIM];
            {
                const float4* c4 = (const float4*)(cb + (size_t)k * DIM);
#pragma unroll
                for (int j = 0; j < 16; ++j) {
                    float4 v = c4[j];
                    cr[4 * j + 0] = v.x; cr[4 * j + 1] = v.y;
                    cr[4 * j + 2] = v.z; cr[4 * j + 3] = v.w;
                }
            }
            float e = np_dot64(zr, cr);
            float dd;
            {
#pragma clang fp contract(off)
                float t1 = s_z + bnorm[k];
                float mm = 2.0f * e;
                dd = t1 - mm;
            }
            if (dd < m1) { m1 = dd; best = k; }   // ascending k: first occurrence
        }
        // cross-lane argmin; exact-tie -> smaller index (numpy first-occurrence)
#pragma unroll
        for (int off = 32; off > 0; off >>= 1) {
            float od = __shfl_down(m1, off);
            int ob = __shfl_down(best, off);
            if (od < m1 || (od == m1 && ob < best)) { m1 = od; best = ob; }
        }
        best = __shfl(best, 0);

        const float zl = zr[lane];
        const float zq = cb[(size_t)best * DIM + lane];
        float d, o;
        {
#pragma clang fp contract(off)
            d = zq - zl;
            o = zl + d;
        }
        out[(size_t)t * DIM + lane] = o;
        float l2 = d * d;
#pragma unroll
        for (int off = 32; off > 0; off >>= 1)
            l2 += __shfl_down(l2, off);
        if (lane == 0) {
            out[OUT_IDX_OFF + t] = (float)best;
            atomicAdd(loss_sum, (double)l2);
        }
    }
}

__global__ void vq_loss_final(const double* __restrict__ loss_sum,
                              float* __restrict__ out) {
    out[OUT_LOSS_OFF] = (float)(2.0 * (*loss_sum) / (double)((size_t)TOKENS * DIM));
}

extern "C" void kernel_launch(void* const* d_in, const int* in_sizes, int n_in,
                              void* d_out, int out_size, void* d_ws, size_t ws_size,
                              hipStream_t stream) {
    const float* z  = (const float*)d_in[0];   // [8,8192,64] f32
    const float* cb = (const float*)d_in[1];   // [1024,64] f32
    float* out = (float*)d_out;

    double* loss_sum = (double*)d_ws;
    unsigned int* flag_count = (unsigned int*)((char*)d_ws + 8);
    float* bnorm = (float*)((char*)d_ws + 16);
    int* flag_list = (int*)((char*)d_ws + 16 + 4096);
    unsigned int cap = 0;
    if (ws_size > 4112 + 4) {
        size_t c = (ws_size - 4112) / 4;
        cap = (c > TOKENS) ? TOKENS : (unsigned int)c;
    }

    hipMemsetAsync(d_ws, 0, 16, stream);
    vq_bnorm<<<dim3(NCODE / 256), dim3(256), 0, stream>>>(cb, bnorm);
    vq_fast<<<dim3(TOKENS / 64), dim3(256), 0, stream>>>(
        z, cb, bnorm, out, flag_count, flag_list, loss_sum, cap);
    vq_exact<<<dim3(256), dim3(256), 0, stream>>>(
        z, cb, bnorm, out, flag_count, flag_list, loss_sum, cap);
    vq_loss_final<<<dim3(1), dim3(1), 0, stream>>>(loss_sum, out);
}

// Round 4
// 359.678 us; speedup vs baseline: 1.4902x; 1.4902x over previous
//
#include <hip/hip_runtime.h>

#define TOKENS 65536
#define DIM 64
#define NCODE 1024
#define MARGIN 2.5e-4f

#define OUT_IDX_OFF ((size_t)TOKENS * DIM)          // 4194304
#define OUT_LOSS_OFF (OUT_IDX_OFF + TOKENS)         // 4259840

// ws layout (bytes):
#define WS_LOSS   0        // double
#define WS_FLAGC  8        // uint
#define WS_BNORM  16       // f32[1024]        -> ends 4112
#define WS_BNF    4224     // f32[16384]       -> ends 69760   (bnorm in C-frag layout)
#define WS_CHI    69760    // ushort[65536]    -> ends 200832  (codebook -2c hi, A-frag layout)
#define WS_CLO    200832   // ushort[65536]    -> ends 331904  (codebook -2c lo)
#define WS_FLAGS  331904   // int flag_list[]

typedef __attribute__((ext_vector_type(8))) short short8;
typedef __attribute__((ext_vector_type(4))) float f32x4;

// ---------------------------------------------------------------------------
// numpy-bitwise f32 sum-of-squares — VERIFIED absmax=0 (round 2). Do not touch.
// ---------------------------------------------------------------------------
__device__ __forceinline__ float np_sumsq64(const float* __restrict__ x) {
#pragma clang fp contract(off)
    float r[8];
#pragma unroll
    for (int j = 0; j < 8; ++j) r[j] = x[j] * x[j];
#pragma unroll
    for (int i = 8; i < 64; i += 8) {
#pragma unroll
        for (int j = 0; j < 8; ++j) {
            float sq = x[i + j] * x[i + j];
            r[j] = r[j] + sq;
        }
    }
    return ((r[0] + r[1]) + (r[2] + r[3])) + ((r[4] + r[5]) + (r[6] + r[7]));
}

__global__ __launch_bounds__(256) void vq_bnorm(const float* __restrict__ cb,
                                                float* __restrict__ bnorm) {
    int k = blockIdx.x * 256 + threadIdx.x;
    bnorm[k] = np_sumsq64(cb + (size_t)k * DIM);
}

// ---------------------------------------------------------------------------
// Prep: codebook -> bf16 hi/lo A-fragments of (-2*C), plus bnorm in C-layout.
// A-frag element (chunk c, step s, lane L, j):
//   value = split(-2 * cb[c*16 + (L&15)][s*32 + (L>>4)*8 + j])
//   linear index = ((c*2+s)*64 + L)*8 + j
// bnorm C-frag: idx = chunk*256 + lane*4 + i = bnorm[chunk*16 + (lane>>4)*4 + i]
// ---------------------------------------------------------------------------
__global__ __launch_bounds__(256) void vq_prep(
    const float* __restrict__ cb, const float* __restrict__ bnorm,
    unsigned short* __restrict__ chi, unsigned short* __restrict__ clo,
    float* __restrict__ bnf) {
    int tid = blockIdx.x * 256 + threadIdx.x;   // 0..65535
    int j = tid & 7;
    int L = (tid >> 3) & 63;
    int cs = tid >> 9;          // 0..127
    int s = cs & 1, c = cs >> 1;
    int code = c * 16 + (L & 15);
    int d = s * 32 + (L >> 4) * 8 + j;
    float v = -2.0f * cb[(size_t)code * DIM + d];
    unsigned int b = __float_as_uint(v);
    chi[tid] = (unsigned short)(b >> 16);                       // truncation split
    float hf = __uint_as_float(b & 0xFFFF0000u);
    float lo;
    {
#pragma clang fp contract(off)
        lo = v - hf;                                            // exact in f32
    }
    clo[tid] = (unsigned short)(__float_as_uint(lo) >> 16);

    if (tid < 16384) {
        int i = tid & 3, lane = (tid >> 2) & 63, cc = tid >> 8;
        bnf[tid] = bnorm[cc * 16 + ((lane >> 4) * 4) + i];
    }
}

__device__ __forceinline__ void top2_merge(float& a1, float& a2, int& ai,
                                           float b1, float b2, int bi) {
    float n1 = fminf(a1, b1);
    float n2 = fminf(fmaxf(a1, b1), fminf(a2, b2));
    ai = (b1 < a1) ? bi : ai;   // ties keep a (exact ties get flagged anyway)
    a1 = n1; a2 = n2;
}

// ---------------------------------------------------------------------------
// Fast screen via bf16 hi/lo split MFMA.
// Block = 4 waves, 64 tokens. Wave w: 64 tokens (4 col-tiles of 16) x codes
// [w*256, w*256+256) in 16-code chunks. acc = bnorm + (-2c_hi)z_hi +
// (-2c_lo)z_hi + (-2c_hi)z_lo  ==  u = ||c||^2 - 2 z.c  (split error ~3e-6).
// C layout: col=lane&15 (token), row=quad*4+reg (code) -> top-2 is in-lane.
// ---------------------------------------------------------------------------
__global__ __launch_bounds__(256) void vq_fast(
    const float* __restrict__ z, const float* __restrict__ cb,
    const unsigned short* __restrict__ cfrag_hi,
    const unsigned short* __restrict__ cfrag_lo,
    const float* __restrict__ bnorm_frag, float* __restrict__ out,
    unsigned int* __restrict__ flag_count, int* __restrict__ flag_list,
    double* __restrict__ loss_sum, unsigned int flag_cap) {
    __shared__ float sm1[4][64];
    __shared__ float sm2[4][64];
    __shared__ int   sbi[4][64];
    __shared__ int   s_best[64];
    __shared__ int   s_flag[64];

    const int tid = threadIdx.x;
    const int lane = tid & 63;
    const int w = tid >> 6;
    const int t0 = blockIdx.x * 64;
    const int col = lane & 15;
    const int quad = lane >> 4;

    // Build token B-fragments (bf16 hi/lo), 4 tiles x 2 K-steps, in registers.
    short8 zhi[4][2], zlo[4][2];
#pragma unroll
    for (int tt = 0; tt < 4; ++tt) {
#pragma unroll
        for (int s = 0; s < 2; ++s) {
            const float* zp = z + (size_t)(t0 + tt * 16 + col) * DIM + s * 32 + quad * 8;
            float4 f0 = ((const float4*)zp)[0];
            float4 f1 = ((const float4*)zp)[1];
            float f[8] = {f0.x, f0.y, f0.z, f0.w, f1.x, f1.y, f1.z, f1.w};
            short8 h, l;
#pragma unroll
            for (int j = 0; j < 8; ++j) {
                unsigned int b = __float_as_uint(f[j]);
                h[j] = (short)(b >> 16);
                float hf = __uint_as_float(b & 0xFFFF0000u);
                float lo;
                {
#pragma clang fp contract(off)
                    lo = f[j] - hf;
                }
                l[j] = (short)(__float_as_uint(lo) >> 16);
            }
            zhi[tt][s] = h; zlo[tt][s] = l;
        }
    }

    float m1[4], m2[4];
    int bi[4];
#pragma unroll
    for (int tt = 0; tt < 4; ++tt) { m1[tt] = 3.0e38f; m2[tt] = 3.0e38f; bi[tt] = 0; }

    const int koff = quad * 4;
    const short8* CH = (const short8*)cfrag_hi;
    const short8* CL = (const short8*)cfrag_lo;
    const f32x4* BN = (const f32x4*)bnorm_frag;

    for (int m = 0; m < 16; ++m) {
        const int c = w * 16 + m;
        short8 ch0 = CH[(c * 2 + 0) * 64 + lane];
        short8 ch1 = CH[(c * 2 + 1) * 64 + lane];
        short8 cl0 = CL[(c * 2 + 0) * 64 + lane];
        short8 cl1 = CL[(c * 2 + 1) * 64 + lane];
        f32x4 bn = BN[c * 64 + lane];
        const int cbase = c * 16 + koff;
#pragma unroll
        for (int tt = 0; tt < 4; ++tt) {
            f32x4 acc = bn;
            acc = __builtin_amdgcn_mfma_f32_16x16x32_bf16(ch0, zhi[tt][0], acc, 0, 0, 0);
            acc = __builtin_amdgcn_mfma_f32_16x16x32_bf16(cl0, zhi[tt][0], acc, 0, 0, 0);
            acc = __builtin_amdgcn_mfma_f32_16x16x32_bf16(ch0, zlo[tt][0], acc, 0, 0, 0);
            acc = __builtin_amdgcn_mfma_f32_16x16x32_bf16(ch1, zhi[tt][1], acc, 0, 0, 0);
            acc = __builtin_amdgcn_mfma_f32_16x16x32_bf16(cl1, zhi[tt][1], acc, 0, 0, 0);
            acc = __builtin_amdgcn_mfma_f32_16x16x32_bf16(ch1, zlo[tt][1], acc, 0, 0, 0);
#pragma unroll
            for (int i = 0; i < 4; ++i) {
                float u = acc[i];
                float om1 = m1[tt];
                bool lt = u < om1;
                float fm = fminf(m2[tt], u);
                m2[tt] = lt ? om1 : fm;
                m1[tt] = lt ? u : om1;
                bi[tt] = lt ? (cbase + i) : bi[tt];
            }
        }
    }

    // in-wave quad merge (lanes l, l+16, l+32, l+48 hold same token col)
#pragma unroll
    for (int tt = 0; tt < 4; ++tt) {
        float a1 = m1[tt], a2 = m2[tt];
        int ai = bi[tt];
        {
            float o1 = __shfl_xor(a1, 16); float o2 = __shfl_xor(a2, 16);
            int oi = __shfl_xor(ai, 16);
            top2_merge(a1, a2, ai, o1, o2, oi);
        }
        {
            float o1 = __shfl_xor(a1, 32); float o2 = __shfl_xor(a2, 32);
            int oi = __shfl_xor(ai, 32);
            top2_merge(a1, a2, ai, o1, o2, oi);
        }
        if (lane < 16) {
            sm1[w][tt * 16 + lane] = a1;
            sm2[w][tt * 16 + lane] = a2;
            sbi[w][tt * 16 + lane] = ai;
        }
    }
    __syncthreads();

    // block merge across the 4 waves' code ranges; flag near-ties
    if (tid < 64) {
        float M1 = sm1[0][tid], M2 = sm2[0][tid];
        int B = sbi[0][tid];
#pragma unroll
        for (int q = 1; q < 4; ++q)
            top2_merge(M1, M2, B, sm1[q][tid], sm2[q][tid], sbi[q][tid]);
        int fl = (M2 - M1) < MARGIN;
        if (fl) {
            unsigned int pos = atomicAdd(flag_count, 1u);
            if (pos >= flag_cap) fl = 0;
            else flag_list[pos] = t0 + tid;
        }
        s_best[tid] = B;
        s_flag[tid] = fl;
    }
    __syncthreads();

    // epilogue: 4 threads per token; flagged tokens deferred to exact pass
    const int et = tid >> 2, eq = tid & 3;
    float loss_t = 0.0f;
    if (!s_flag[et]) {
        const int B = s_best[et];
        const float4* cq  = (const float4*)(cb + (size_t)B * DIM + eq * 16);
        const float4* zq4 = (const float4*)(z + (size_t)(t0 + et) * DIM + eq * 16);
        float4* o4 = (float4*)(out + (size_t)(t0 + et) * DIM + eq * 16);
#pragma unroll
        for (int jj = 0; jj < 4; ++jj) {
#pragma clang fp contract(off)
            float4 cc = cq[jj];
            float4 zz = zq4[jj];
            float d0 = cc.x - zz.x, d1 = cc.y - zz.y;
            float d2 = cc.z - zz.z, d3 = cc.w - zz.w;
            float4 o;
            o.x = zz.x + d0; o.y = zz.y + d1;
            o.z = zz.z + d2; o.w = zz.w + d3;
            o4[jj] = o;
            loss_t = __fmaf_rn(d0, d0, loss_t);
            loss_t = __fmaf_rn(d1, d1, loss_t);
            loss_t = __fmaf_rn(d2, d2, loss_t);
            loss_t = __fmaf_rn(d3, d3, loss_t);
        }
        if (eq == 0) out[OUT_IDX_OFF + t0 + et] = (float)B;
    }
#pragma unroll
    for (int off = 32; off > 0; off >>= 1)
        loss_t += __shfl_down(loss_t, off);
    if (lane == 0) atomicAdd(loss_sum, (double)loss_t);
}

// ---------------------------------------------------------------------------
// Exact numpy-bitwise pass for flagged tokens. One wave/token, lane l handles
// codes [l*16, l*16+16). Spill-free restructure: code rows loaded in 4-float4
// groups; arithmetic op-order identical to round-2-verified np_dot64.
// ---------------------------------------------------------------------------
__global__ __launch_bounds__(256) void vq_exact(
    const float* __restrict__ z, const float* __restrict__ cb,
    const float* __restrict__ bnorm, float* __restrict__ out,
    const unsigned int* __restrict__ flag_count,
    const int* __restrict__ flag_list, double* __restrict__ loss_sum,
    unsigned int flag_cap) {
    const int lane = threadIdx.x & 63;
    unsigned int count = *flag_count;
    if (count > flag_cap) count = flag_cap;
    const unsigned int gw = blockIdx.x * 4 + (threadIdx.x >> 6);
    const unsigned int NW = gridDim.x * 4;

    for (unsigned int li = gw; li < count; li += NW) {
        const int t = flag_list[li];
        float zr[DIM];
        {
            const float4* z4 = (const float4*)(z + (size_t)t * DIM);
#pragma unroll
            for (int j = 0; j < 16; ++j) {
                float4 v = z4[j];
                zr[4 * j + 0] = v.x; zr[4 * j + 1] = v.y;
                zr[4 * j + 2] = v.z; zr[4 * j + 3] = v.w;
            }
        }
        const float s_z = np_sumsq64(zr);

        float m1 = 3.0e38f;
        int best = 0;
        for (int c = 0; c < 16; ++c) {
            const int k = lane * 16 + c;
            const float4* c4 = (const float4*)(cb + (size_t)k * DIM);
            float l16[16];
#pragma unroll
            for (int g = 0; g < 4; ++g) {
                float4 v0 = c4[g], v1 = c4[4 + g], v2 = c4[8 + g], v3 = c4[12 + g];
                float q0[4] = {v0.x, v0.y, v0.z, v0.w};
                float q1[4] = {v1.x, v1.y, v1.z, v1.w};
                float q2[4] = {v2.x, v2.y, v2.z, v2.w};
                float q3[4] = {v3.x, v3.y, v3.z, v3.w};
#pragma unroll
                for (int e = 0; e < 4; ++e) {
#pragma clang fp contract(off)
                    int j = 4 * g + e;
                    float acc = zr[48 + j] * q3[e];
                    acc = __fmaf_rn(zr[32 + j], q2[e], acc);
                    acc = __fmaf_rn(zr[16 + j], q1[e], acc);
                    acc = __fmaf_rn(zr[j],      q0[e], acc);
                    l16[j] = acc;
                }
            }
            float e_np;
            {
#pragma clang fp contract(off)
#pragma unroll
                for (int j = 0; j < 8; ++j) l16[j] = l16[j] + l16[j + 8];
#pragma unroll
                for (int j = 0; j < 4; ++j) l16[j] = l16[j] + l16[j + 4];
                l16[0] = l16[0] + l16[2];
                l16[1] = l16[1] + l16[3];
                e_np = l16[0] + l16[1];
            }
            float dd;
            {
#pragma clang fp contract(off)
                float t1 = s_z + bnorm[k];
                float mm = 2.0f * e_np;
                dd = t1 - mm;
            }
            if (dd < m1) { m1 = dd; best = k; }
        }
#pragma unroll
        for (int off = 32; off > 0; off >>= 1) {
            float od = __shfl_down(m1, off);
            int ob = __shfl_down(best, off);
            if (od < m1 || (od == m1 && ob < best)) { m1 = od; best = ob; }
        }
        best = __shfl(best, 0);

        const float zl = zr[lane];
        const float zq = cb[(size_t)best * DIM + lane];
        float d, o;
        {
#pragma clang fp contract(off)
            d = zq - zl;
            o = zl + d;
        }
        out[(size_t)t * DIM + lane] = o;
        float l2 = d * d;
#pragma unroll
        for (int off = 32; off > 0; off >>= 1)
            l2 += __shfl_down(l2, off);
        if (lane == 0) {
            out[OUT_IDX_OFF + t] = (float)best;
            atomicAdd(loss_sum, (double)l2);
        }
    }
}

__global__ void vq_loss_final(const double* __restrict__ loss_sum,
                              float* __restrict__ out) {
    out[OUT_LOSS_OFF] = (float)(2.0 * (*loss_sum) / (double)((size_t)TOKENS * DIM));
}

extern "C" void kernel_launch(void* const* d_in, const int* in_sizes, int n_in,
                              void* d_out, int out_size, void* d_ws, size_t ws_size,
                              hipStream_t stream) {
    const float* z  = (const float*)d_in[0];   // [8,8192,64] f32
    const float* cb = (const float*)d_in[1];   // [1024,64] f32
    float* out = (float*)d_out;

    char* ws = (char*)d_ws;
    double* loss_sum = (double*)(ws + WS_LOSS);
    unsigned int* flag_count = (unsigned int*)(ws + WS_FLAGC);
    float* bnorm = (float*)(ws + WS_BNORM);
    float* bnf = (float*)(ws + WS_BNF);
    unsigned short* chi = (unsigned short*)(ws + WS_CHI);
    unsigned short* clo = (unsigned short*)(ws + WS_CLO);
    int* flag_list = (int*)(ws + WS_FLAGS);
    unsigned int cap = 0;
    if (ws_size > WS_FLAGS + 4) {
        size_t c = (ws_size - WS_FLAGS) / 4;
        cap = (c > TOKENS) ? TOKENS : (unsigned int)c;
    }

    hipMemsetAsync(d_ws, 0, 16, stream);
    vq_bnorm<<<dim3(NCODE / 256), dim3(256), 0, stream>>>(cb, bnorm);
    vq_prep<<<dim3(256), dim3(256), 0, stream>>>(cb, bnorm, chi, clo, bnf);
    vq_fast<<<dim3(TOKENS / 64), dim3(256), 0, stream>>>(
        z, cb, chi, clo, bnf, out, flag_count, flag_list, loss_sum, cap);
    vq_exact<<<dim3(256), dim3(256), 0, stream>>>(
        z, cb, bnorm, out, flag_count, flag_list, loss_sum, cap);
    vq_loss_final<<<dim3(1), dim3(1), 0, stream>>>(loss_sum, out);
}

// Round 5
// 306.470 us; speedup vs baseline: 1.7489x; 1.1736x over previous
//
#include <hip/hip_runtime.h>

#define TOKENS 65536
#define DIM 64
#define NCODE 1024
#define MARGIN 2.5e-4f

#define OUT_IDX_OFF ((size_t)TOKENS * DIM)          // 4194304
#define OUT_LOSS_OFF (OUT_IDX_OFF + TOKENS)         // 4259840

// ws layout (bytes):
#define WS_LOSS   0        // double
#define WS_FLAGC  8        // uint
#define WS_BNORM  16       // f32[1024]        -> ends 4112
#define WS_BNF    4224     // f32[16384]       -> ends 69760   (bnorm in C-frag layout)
#define WS_CHI    69760    // ushort[65536]    -> ends 200832  (codebook -2c hi, A-frag layout)
#define WS_CLO    200832   // ushort[65536]    -> ends 331904  (codebook -2c lo)
#define WS_FLAGS  331904   // int flag_list[]

typedef __attribute__((ext_vector_type(8))) short short8;
typedef __attribute__((ext_vector_type(4))) float f32x4;

// ---------------------------------------------------------------------------
// numpy-bitwise f32 sum-of-squares — VERIFIED absmax=0 (round 2). Do not touch.
// ---------------------------------------------------------------------------
__device__ __forceinline__ float np_sumsq64(const float* __restrict__ x) {
#pragma clang fp contract(off)
    float r[8];
#pragma unroll
    for (int j = 0; j < 8; ++j) r[j] = x[j] * x[j];
#pragma unroll
    for (int i = 8; i < 64; i += 8) {
#pragma unroll
        for (int j = 0; j < 8; ++j) {
            float sq = x[i + j] * x[i + j];
            r[j] = r[j] + sq;
        }
    }
    return ((r[0] + r[1]) + (r[2] + r[3])) + ((r[4] + r[5]) + (r[6] + r[7]));
}

__global__ __launch_bounds__(256) void vq_bnorm(const float* __restrict__ cb,
                                                float* __restrict__ bnorm) {
    int k = blockIdx.x * 256 + threadIdx.x;
    bnorm[k] = np_sumsq64(cb + (size_t)k * DIM);
}

// ---------------------------------------------------------------------------
// Prep: codebook -> bf16 hi/lo A-fragments of (-2*C), plus bnorm in C-layout.
// (verified absmax=0 in round 4)
// ---------------------------------------------------------------------------
__global__ __launch_bounds__(256) void vq_prep(
    const float* __restrict__ cb, const float* __restrict__ bnorm,
    unsigned short* __restrict__ chi, unsigned short* __restrict__ clo,
    float* __restrict__ bnf) {
    int tid = blockIdx.x * 256 + threadIdx.x;   // 0..65535
    int j = tid & 7;
    int L = (tid >> 3) & 63;
    int cs = tid >> 9;          // 0..127
    int s = cs & 1, c = cs >> 1;
    int code = c * 16 + (L & 15);
    int d = s * 32 + (L >> 4) * 8 + j;
    float v = -2.0f * cb[(size_t)code * DIM + d];
    unsigned int b = __float_as_uint(v);
    chi[tid] = (unsigned short)(b >> 16);                       // truncation split
    float hf = __uint_as_float(b & 0xFFFF0000u);
    float lo;
    {
#pragma clang fp contract(off)
        lo = v - hf;                                            // exact in f32
    }
    clo[tid] = (unsigned short)(__float_as_uint(lo) >> 16);

    if (tid < 16384) {
        int i = tid & 3, lane = (tid >> 2) & 63, cc = tid >> 8;
        bnf[tid] = bnorm[cc * 16 + ((lane >> 4) * 4) + i];
    }
}

__device__ __forceinline__ void top2_merge(float& a1, float& a2, int& ai,
                                           float b1, float b2, int bi) {
    float n1 = fminf(a1, b1);
    float n2 = fminf(fmaxf(a1, b1), fminf(a2, b2));
    ai = (b1 < a1) ? bi : ai;   // ties keep a (exact ties get flagged anyway)
    a1 = n1; a2 = n2;
}

// ---------------------------------------------------------------------------
// Fast screen via bf16 hi/lo split MFMA (layout verified absmax=0 round 4).
// Changes this round: __launch_bounds__(256,1) to kill spills; 1-chunk
// software prefetch of A-fragments + bnorm.
// ---------------------------------------------------------------------------
__global__ __launch_bounds__(256, 1) void vq_fast(
    const float* __restrict__ z, const float* __restrict__ cb,
    const unsigned short* __restrict__ cfrag_hi,
    const unsigned short* __restrict__ cfrag_lo,
    const float* __restrict__ bnorm_frag, float* __restrict__ out,
    unsigned int* __restrict__ flag_count, int* __restrict__ flag_list,
    double* __restrict__ loss_sum, unsigned int flag_cap) {
    __shared__ float sm1[4][64];
    __shared__ float sm2[4][64];
    __shared__ int   sbi[4][64];
    __shared__ int   s_best[64];
    __shared__ int   s_flag[64];

    const int tid = threadIdx.x;
    const int lane = tid & 63;
    const int w = tid >> 6;
    const int t0 = blockIdx.x * 64;
    const int col = lane & 15;
    const int quad = lane >> 4;

    // Build token B-fragments (bf16 hi/lo), 4 tiles x 2 K-steps, in registers.
    short8 zhi[4][2], zlo[4][2];
#pragma unroll
    for (int tt = 0; tt < 4; ++tt) {
#pragma unroll
        for (int s = 0; s < 2; ++s) {
            const float* zp = z + (size_t)(t0 + tt * 16 + col) * DIM + s * 32 + quad * 8;
            float4 f0 = ((const float4*)zp)[0];
            float4 f1 = ((const float4*)zp)[1];
            float f[8] = {f0.x, f0.y, f0.z, f0.w, f1.x, f1.y, f1.z, f1.w};
            short8 h, l;
#pragma unroll
            for (int j = 0; j < 8; ++j) {
                unsigned int b = __float_as_uint(f[j]);
                h[j] = (short)(b >> 16);
                float hf = __uint_as_float(b & 0xFFFF0000u);
                float lo;
                {
#pragma clang fp contract(off)
                    lo = f[j] - hf;
                }
                l[j] = (short)(__float_as_uint(lo) >> 16);
            }
            zhi[tt][s] = h; zlo[tt][s] = l;
        }
    }

    float m1[4], m2[4];
    int bi[4];
#pragma unroll
    for (int tt = 0; tt < 4; ++tt) { m1[tt] = 3.0e38f; m2[tt] = 3.0e38f; bi[tt] = 0; }

    const int koff = quad * 4;
    const short8* CH = (const short8*)cfrag_hi;
    const short8* CL = (const short8*)cfrag_lo;
    const f32x4* BN = (const f32x4*)bnorm_frag;

    int c = w * 16;
    short8 ch0 = CH[(c * 2 + 0) * 64 + lane];
    short8 ch1 = CH[(c * 2 + 1) * 64 + lane];
    short8 cl0 = CL[(c * 2 + 0) * 64 + lane];
    short8 cl1 = CL[(c * 2 + 1) * 64 + lane];
    f32x4 bn = BN[c * 64 + lane];

    for (int m = 0; m < 16; ++m) {
        const int cn = (m < 15) ? c + 1 : c;   // last iter: redundant reload
        short8 nh0 = CH[(cn * 2 + 0) * 64 + lane];
        short8 nh1 = CH[(cn * 2 + 1) * 64 + lane];
        short8 nl0 = CL[(cn * 2 + 0) * 64 + lane];
        short8 nl1 = CL[(cn * 2 + 1) * 64 + lane];
        f32x4 nbn = BN[cn * 64 + lane];

        const int cbase = c * 16 + koff;
#pragma unroll
        for (int tt = 0; tt < 4; ++tt) {
            f32x4 acc = bn;
            acc = __builtin_amdgcn_mfma_f32_16x16x32_bf16(ch0, zhi[tt][0], acc, 0, 0, 0);
            acc = __builtin_amdgcn_mfma_f32_16x16x32_bf16(cl0, zhi[tt][0], acc, 0, 0, 0);
            acc = __builtin_amdgcn_mfma_f32_16x16x32_bf16(ch0, zlo[tt][0], acc, 0, 0, 0);
            acc = __builtin_amdgcn_mfma_f32_16x16x32_bf16(ch1, zhi[tt][1], acc, 0, 0, 0);
            acc = __builtin_amdgcn_mfma_f32_16x16x32_bf16(cl1, zhi[tt][1], acc, 0, 0, 0);
            acc = __builtin_amdgcn_mfma_f32_16x16x32_bf16(ch1, zlo[tt][1], acc, 0, 0, 0);
#pragma unroll
            for (int i = 0; i < 4; ++i) {
                float u = acc[i];
                float om1 = m1[tt];
                bool lt = u < om1;
                float fm = fminf(m2[tt], u);
                m2[tt] = lt ? om1 : fm;
                m1[tt] = lt ? u : om1;
                bi[tt] = lt ? (cbase + i) : bi[tt];
            }
        }
        ch0 = nh0; ch1 = nh1; cl0 = nl0; cl1 = nl1; bn = nbn;
        c = cn;
    }

    // in-wave quad merge (lanes l, l^16, l^32, l^48 hold same token col)
#pragma unroll
    for (int tt = 0; tt < 4; ++tt) {
        float a1 = m1[tt], a2 = m2[tt];
        int ai = bi[tt];
        {
            float o1 = __shfl_xor(a1, 16); float o2 = __shfl_xor(a2, 16);
            int oi = __shfl_xor(ai, 16);
            top2_merge(a1, a2, ai, o1, o2, oi);
        }
        {
            float o1 = __shfl_xor(a1, 32); float o2 = __shfl_xor(a2, 32);
            int oi = __shfl_xor(ai, 32);
            top2_merge(a1, a2, ai, o1, o2, oi);
        }
        if (lane < 16) {
            sm1[w][tt * 16 + lane] = a1;
            sm2[w][tt * 16 + lane] = a2;
            sbi[w][tt * 16 + lane] = ai;
        }
    }
    __syncthreads();

    // block merge across the 4 waves' code ranges; flag near-ties
    if (tid < 64) {
        float M1 = sm1[0][tid], M2 = sm2[0][tid];
        int B = sbi[0][tid];
#pragma unroll
        for (int q = 1; q < 4; ++q)
            top2_merge(M1, M2, B, sm1[q][tid], sm2[q][tid], sbi[q][tid]);
        int fl = (M2 - M1) < MARGIN;
        if (fl) {
            unsigned int pos = atomicAdd(flag_count, 1u);
            if (pos >= flag_cap) fl = 0;
            else flag_list[pos] = t0 + tid;
        }
        s_best[tid] = B;
        s_flag[tid] = fl;
    }
    __syncthreads();

    // epilogue: 4 threads per token; flagged tokens deferred to exact pass
    const int et = tid >> 2, eq = tid & 3;
    float loss_t = 0.0f;
    if (!s_flag[et]) {
        const int B = s_best[et];
        const float4* cq  = (const float4*)(cb + (size_t)B * DIM + eq * 16);
        const float4* zq4 = (const float4*)(z + (size_t)(t0 + et) * DIM + eq * 16);
        float4* o4 = (float4*)(out + (size_t)(t0 + et) * DIM + eq * 16);
#pragma unroll
        for (int jj = 0; jj < 4; ++jj) {
#pragma clang fp contract(off)
            float4 cc = cq[jj];
            float4 zz = zq4[jj];
            float d0 = cc.x - zz.x, d1 = cc.y - zz.y;
            float d2 = cc.z - zz.z, d3 = cc.w - zz.w;
            float4 o;
            o.x = zz.x + d0; o.y = zz.y + d1;
            o.z = zz.z + d2; o.w = zz.w + d3;
            o4[jj] = o;
            loss_t = __fmaf_rn(d0, d0, loss_t);
            loss_t = __fmaf_rn(d1, d1, loss_t);
            loss_t = __fmaf_rn(d2, d2, loss_t);
            loss_t = __fmaf_rn(d3, d3, loss_t);
        }
        if (eq == 0) out[OUT_IDX_OFF + t0 + et] = (float)B;
    }
#pragma unroll
    for (int off = 32; off > 0; off >>= 1)
        loss_t += __shfl_down(loss_t, off);
    if (lane == 0) atomicAdd(loss_sum, (double)loss_t);
}

// ---------------------------------------------------------------------------
// Exact numpy-bitwise pass for flagged tokens. One wave/token, lane l handles
// codes [l*16, l*16+16). Spill-proof: z lives in LDS (broadcast reads — all
// lanes read the same address), uniform trip count for block-wide barriers.
// Arithmetic op order identical to the round-2-verified bitwise scheme.
// ---------------------------------------------------------------------------
__global__ __launch_bounds__(256) void vq_exact(
    const float* __restrict__ z, const float* __restrict__ cb,
    const float* __restrict__ bnorm, float* __restrict__ out,
    const unsigned int* __restrict__ flag_count,
    const int* __restrict__ flag_list, double* __restrict__ loss_sum,
    unsigned int flag_cap) {
    __shared__ float zsh[4][DIM];
    const int w = threadIdx.x >> 6;
    const int lane = threadIdx.x & 63;
    unsigned int count = *flag_count;
    if (count > flag_cap) count = flag_cap;
    const unsigned int gw = blockIdx.x * 4 + w;
    const unsigned int NW = gridDim.x * 4;
    const unsigned int trips = (count + NW - 1) / NW;   // uniform across block

    for (unsigned int j = 0; j < trips; ++j) {
        const unsigned int li = gw + j * NW;
        const int t = (li < count) ? flag_list[li] : -1;
        const float zl = (t >= 0) ? z[(size_t)t * DIM + lane] : 0.0f;
        __syncthreads();
        zsh[w][lane] = zl;
        __syncthreads();
        if (t >= 0) {
            const float* zr = zsh[w];
            const float s_z = np_sumsq64(zr);

            float m1 = 3.0e38f;
            int best = 0;
            for (int cc = 0; cc < 16; ++cc) {
                const int k = lane * 16 + cc;
                const float4* c4 = (const float4*)(cb + (size_t)k * DIM);
                float l16[16];
#pragma unroll
                for (int g = 0; g < 4; ++g) {
                    float4 v0 = c4[g], v1 = c4[4 + g], v2 = c4[8 + g], v3 = c4[12 + g];
                    float q0[4] = {v0.x, v0.y, v0.z, v0.w};
                    float q1[4] = {v1.x, v1.y, v1.z, v1.w};
                    float q2[4] = {v2.x, v2.y, v2.z, v2.w};
                    float q3[4] = {v3.x, v3.y, v3.z, v3.w};
#pragma unroll
                    for (int e = 0; e < 4; ++e) {
#pragma clang fp contract(off)
                        int jj = 4 * g + e;
                        float acc = zr[48 + jj] * q3[e];
                        acc = __fmaf_rn(zr[32 + jj], q2[e], acc);
                        acc = __fmaf_rn(zr[16 + jj], q1[e], acc);
                        acc = __fmaf_rn(zr[jj],      q0[e], acc);
                        l16[jj] = acc;
                    }
                }
                float e_np;
                {
#pragma clang fp contract(off)
#pragma unroll
                    for (int jj = 0; jj < 8; ++jj) l16[jj] = l16[jj] + l16[jj + 8];
#pragma unroll
                    for (int jj = 0; jj < 4; ++jj) l16[jj] = l16[jj] + l16[jj + 4];
                    l16[0] = l16[0] + l16[2];
                    l16[1] = l16[1] + l16[3];
                    e_np = l16[0] + l16[1];
                }
                float dd;
                {
#pragma clang fp contract(off)
                    float t1 = s_z + bnorm[k];
                    float mm = 2.0f * e_np;
                    dd = t1 - mm;
                }
                if (dd < m1) { m1 = dd; best = k; }
            }
#pragma unroll
            for (int off = 32; off > 0; off >>= 1) {
                float od = __shfl_down(m1, off);
                int ob = __shfl_down(best, off);
                if (od < m1 || (od == m1 && ob < best)) { m1 = od; best = ob; }
            }
            best = __shfl(best, 0);

            const float zq = cb[(size_t)best * DIM + lane];
            float d, o;
            {
#pragma clang fp contract(off)
                d = zq - zl;
                o = zl + d;
            }
            out[(size_t)t * DIM + lane] = o;
            float l2 = d * d;
#pragma unroll
            for (int off = 32; off > 0; off >>= 1)
                l2 += __shfl_down(l2, off);
            if (lane == 0) {
                out[OUT_IDX_OFF + t] = (float)best;
                atomicAdd(loss_sum, (double)l2);
            }
        }
    }
}

__global__ void vq_loss_final(const double* __restrict__ loss_sum,
                              float* __restrict__ out) {
    out[OUT_LOSS_OFF] = (float)(2.0 * (*loss_sum) / (double)((size_t)TOKENS * DIM));
}

extern "C" void kernel_launch(void* const* d_in, const int* in_sizes, int n_in,
                              void* d_out, int out_size, void* d_ws, size_t ws_size,
                              hipStream_t stream) {
    const float* z  = (const float*)d_in[0];   // [8,8192,64] f32
    const float* cb = (const float*)d_in[1];   // [1024,64] f32
    float* out = (float*)d_out;

    char* ws = (char*)d_ws;
    double* loss_sum = (double*)(ws + WS_LOSS);
    unsigned int* flag_count = (unsigned int*)(ws + WS_FLAGC);
    float* bnorm = (float*)(ws + WS_BNORM);
    float* bnf = (float*)(ws + WS_BNF);
    unsigned short* chi = (unsigned short*)(ws + WS_CHI);
    unsigned short* clo = (unsigned short*)(ws + WS_CLO);
    int* flag_list = (int*)(ws + WS_FLAGS);
    unsigned int cap = 0;
    if (ws_size > WS_FLAGS + 4) {
        size_t c = (ws_size - WS_FLAGS) / 4;
        cap = (c > TOKENS) ? TOKENS : (unsigned int)c;
    }

    hipMemsetAsync(d_ws, 0, 16, stream);
    vq_bnorm<<<dim3(NCODE / 256), dim3(256), 0, stream>>>(cb, bnorm);
    vq_prep<<<dim3(256), dim3(256), 0, stream>>>(cb, bnorm, chi, clo, bnf);
    vq_fast<<<dim3(TOKENS / 64), dim3(256), 0, stream>>>(
        z, cb, chi, clo, bnf, out, flag_count, flag_list, loss_sum, cap);
    vq_exact<<<dim3(256), dim3(256), 0, stream>>>(
        z, cb, bnorm, out, flag_count, flag_list, loss_sum, cap);
    vq_loss_final<<<dim3(1), dim3(1), 0, stream>>>(loss_sum, out);
}

// Round 6
// 277.046 us; speedup vs baseline: 1.9346x; 1.1062x over previous
//
#include <hip/hip_runtime.h>

#define TOKENS 65536
#define DIM 64
#define NCODE 1024
#define MARGIN 2.5e-4f
#define FLAG_CAP 8192

#define OUT_IDX_OFF ((size_t)TOKENS * DIM)          // 4194304
#define OUT_LOSS_OFF (OUT_IDX_OFF + TOKENS)         // 4259840

// ws layout (bytes):
#define WS_LOSS   0        // double
#define WS_FLAGC  8        // uint
#define WS_BNORM  16       // f32[1024]      -> 4112
#define WS_BNF    4224     // f32[16384]     -> 69760  (bnorm in C-frag layout)
#define WS_CHI    69760    // ushort[65536]  -> 200832 (codebook -2c hi, A-frag)
#define WS_CLO    200832   // ushort[65536]  -> 331904 (codebook -2c lo)
#define WS_PACKED 331904   // u64[8192]      -> 397440 (per-flagged argmin)
#define WS_FLAGS  397440   // int[8192]      -> 430208

typedef __attribute__((ext_vector_type(8))) short short8;
typedef __attribute__((ext_vector_type(4))) float f32x4;

// ---------------------------------------------------------------------------
// numpy-bitwise f32 sum-of-squares — VERIFIED absmax=0 (round 2). Do not touch.
// ---------------------------------------------------------------------------
__device__ __forceinline__ float np_sumsq64(const float* __restrict__ x) {
#pragma clang fp contract(off)
    float r[8];
#pragma unroll
    for (int j = 0; j < 8; ++j) r[j] = x[j] * x[j];
#pragma unroll
    for (int i = 8; i < 64; i += 8) {
#pragma unroll
        for (int j = 0; j < 8; ++j) {
            float sq = x[i + j] * x[i + j];
            r[j] = r[j] + sq;
        }
    }
    return ((r[0] + r[1]) + (r[2] + r[3])) + ((r[4] + r[5]) + (r[6] + r[7]));
}

__global__ __launch_bounds__(256) void vq_bnorm(const float* __restrict__ cb,
                                                float* __restrict__ bnorm) {
    int k = blockIdx.x * 256 + threadIdx.x;
    bnorm[k] = np_sumsq64(cb + (size_t)k * DIM);
}

// ---------------------------------------------------------------------------
// Prep: codebook -> bf16 hi/lo A-fragments of (-2*C) + bnorm in C-frag layout.
// (verified absmax=0 rounds 4-5)
// ---------------------------------------------------------------------------
__global__ __launch_bounds__(256) void vq_prep(
    const float* __restrict__ cb, const float* __restrict__ bnorm,
    unsigned short* __restrict__ chi, unsigned short* __restrict__ clo,
    float* __restrict__ bnf) {
    int tid = blockIdx.x * 256 + threadIdx.x;   // 0..65535
    int j = tid & 7;
    int L = (tid >> 3) & 63;
    int cs = tid >> 9;          // 0..127
    int s = cs & 1, c = cs >> 1;
    int code = c * 16 + (L & 15);
    int d = s * 32 + (L >> 4) * 8 + j;
    float v = -2.0f * cb[(size_t)code * DIM + d];
    unsigned int b = __float_as_uint(v);
    chi[tid] = (unsigned short)(b >> 16);                       // truncation split
    float hf = __uint_as_float(b & 0xFFFF0000u);
    float lo;
    {
#pragma clang fp contract(off)
        lo = v - hf;                                            // exact in f32
    }
    clo[tid] = (unsigned short)(__float_as_uint(lo) >> 16);

    if (tid < 16384) {
        int i = tid & 3, lane = (tid >> 2) & 63, cc = tid >> 8;
        bnf[tid] = bnorm[cc * 16 + ((lane >> 4) * 4) + i];
    }
}

__device__ __forceinline__ void top2_merge(float& a1, float& a2, int& ai,
                                           float b1, float b2, int bi) {
    float n1 = fminf(a1, b1);
    float n2 = fminf(fmaxf(a1, b1), fminf(a2, b2));
    ai = (b1 < a1) ? bi : ai;   // ties keep a (exact ties get flagged anyway)
    a1 = n1; a2 = n2;
}

// ---------------------------------------------------------------------------
// Fast screen via bf16 hi/lo split MFMA (numerics verified rounds 4-5).
// Round-6 change: __launch_bounds__(256,2) — live set ~180 VGPR < 256 cap,
// so no spill, and occupancy doubles to 2 blocks/CU (2 waves/SIMD).
// ---------------------------------------------------------------------------
__global__ __launch_bounds__(256, 2) void vq_fast(
    const float* __restrict__ z, const float* __restrict__ cb,
    const unsigned short* __restrict__ cfrag_hi,
    const unsigned short* __restrict__ cfrag_lo,
    const float* __restrict__ bnorm_frag, float* __restrict__ out,
    unsigned int* __restrict__ flag_count, int* __restrict__ flag_list,
    double* __restrict__ loss_sum, unsigned int flag_cap) {
    __shared__ float sm1[4][64];
    __shared__ float sm2[4][64];
    __shared__ int   sbi[4][64];
    __shared__ int   s_best[64];
    __shared__ int   s_flag[64];

    const int tid = threadIdx.x;
    const int lane = tid & 63;
    const int w = tid >> 6;
    const int t0 = blockIdx.x * 64;
    const int col = lane & 15;
    const int quad = lane >> 4;

    // token B-fragments (bf16 hi/lo), 4 tiles x 2 K-steps, in registers
    short8 zhi[4][2], zlo[4][2];
#pragma unroll
    for (int tt = 0; tt < 4; ++tt) {
#pragma unroll
        for (int s = 0; s < 2; ++s) {
            const float* zp = z + (size_t)(t0 + tt * 16 + col) * DIM + s * 32 + quad * 8;
            float4 f0 = ((const float4*)zp)[0];
            float4 f1 = ((const float4*)zp)[1];
            float f[8] = {f0.x, f0.y, f0.z, f0.w, f1.x, f1.y, f1.z, f1.w};
            short8 h, l;
#pragma unroll
            for (int j = 0; j < 8; ++j) {
                unsigned int b = __float_as_uint(f[j]);
                h[j] = (short)(b >> 16);
                float hf = __uint_as_float(b & 0xFFFF0000u);
                float lo;
                {
#pragma clang fp contract(off)
                    lo = f[j] - hf;
                }
                l[j] = (short)(__float_as_uint(lo) >> 16);
            }
            zhi[tt][s] = h; zlo[tt][s] = l;
        }
    }

    float m1[4], m2[4];
    int bi[4];
#pragma unroll
    for (int tt = 0; tt < 4; ++tt) { m1[tt] = 3.0e38f; m2[tt] = 3.0e38f; bi[tt] = 0; }

    const int koff = quad * 4;
    const short8* CH = (const short8*)cfrag_hi;
    const short8* CL = (const short8*)cfrag_lo;
    const f32x4* BN = (const f32x4*)bnorm_frag;

    int c = w * 16;
    short8 ch0 = CH[(c * 2 + 0) * 64 + lane];
    short8 ch1 = CH[(c * 2 + 1) * 64 + lane];
    short8 cl0 = CL[(c * 2 + 0) * 64 + lane];
    short8 cl1 = CL[(c * 2 + 1) * 64 + lane];
    f32x4 bn = BN[c * 64 + lane];

    for (int m = 0; m < 16; ++m) {
        const int cn = (m < 15) ? c + 1 : c;   // last iter: redundant reload
        short8 nh0 = CH[(cn * 2 + 0) * 64 + lane];
        short8 nh1 = CH[(cn * 2 + 1) * 64 + lane];
        short8 nl0 = CL[(cn * 2 + 0) * 64 + lane];
        short8 nl1 = CL[(cn * 2 + 1) * 64 + lane];
        f32x4 nbn = BN[cn * 64 + lane];

        const int cbase = c * 16 + koff;
#pragma unroll
        for (int tt = 0; tt < 4; ++tt) {
            f32x4 acc = bn;
            acc = __builtin_amdgcn_mfma_f32_16x16x32_bf16(ch0, zhi[tt][0], acc, 0, 0, 0);
            acc = __builtin_amdgcn_mfma_f32_16x16x32_bf16(cl0, zhi[tt][0], acc, 0, 0, 0);
            acc = __builtin_amdgcn_mfma_f32_16x16x32_bf16(ch0, zlo[tt][0], acc, 0, 0, 0);
            acc = __builtin_amdgcn_mfma_f32_16x16x32_bf16(ch1, zhi[tt][1], acc, 0, 0, 0);
            acc = __builtin_amdgcn_mfma_f32_16x16x32_bf16(cl1, zhi[tt][1], acc, 0, 0, 0);
            acc = __builtin_amdgcn_mfma_f32_16x16x32_bf16(ch1, zlo[tt][1], acc, 0, 0, 0);
#pragma unroll
            for (int i = 0; i < 4; ++i) {
                float u = acc[i];
                float om1 = m1[tt];
                bool lt = u < om1;
                float fm = fminf(m2[tt], u);
                m2[tt] = lt ? om1 : fm;
                m1[tt] = lt ? u : om1;
                bi[tt] = lt ? (cbase + i) : bi[tt];
            }
        }
        ch0 = nh0; ch1 = nh1; cl0 = nl0; cl1 = nl1; bn = nbn;
        c = cn;
    }

    // in-wave quad merge
#pragma unroll
    for (int tt = 0; tt < 4; ++tt) {
        float a1 = m1[tt], a2 = m2[tt];
        int ai = bi[tt];
        {
            float o1 = __shfl_xor(a1, 16); float o2 = __shfl_xor(a2, 16);
            int oi = __shfl_xor(ai, 16);
            top2_merge(a1, a2, ai, o1, o2, oi);
        }
        {
            float o1 = __shfl_xor(a1, 32); float o2 = __shfl_xor(a2, 32);
            int oi = __shfl_xor(ai, 32);
            top2_merge(a1, a2, ai, o1, o2, oi);
        }
        if (lane < 16) {
            sm1[w][tt * 16 + lane] = a1;
            sm2[w][tt * 16 + lane] = a2;
            sbi[w][tt * 16 + lane] = ai;
        }
    }
    __syncthreads();

    // block merge across the 4 waves' code quarters; flag near-ties
    if (tid < 64) {
        float M1 = sm1[0][tid], M2 = sm2[0][tid];
        int B = sbi[0][tid];
#pragma unroll
        for (int q = 1; q < 4; ++q)
            top2_merge(M1, M2, B, sm1[q][tid], sm2[q][tid], sbi[q][tid]);
        int fl = (M2 - M1) < MARGIN;
        if (fl) {
            unsigned int pos = atomicAdd(flag_count, 1u);
            if (pos >= flag_cap) fl = 0;
            else flag_list[pos] = t0 + tid;
        }
        s_best[tid] = B;
        s_flag[tid] = fl;
    }
    __syncthreads();

    // epilogue: 4 threads per token; flagged tokens deferred
    const int et = tid >> 2, eq = tid & 3;
    float loss_t = 0.0f;
    if (!s_flag[et]) {
        const int B = s_best[et];
        const float4* cq  = (const float4*)(cb + (size_t)B * DIM + eq * 16);
        const float4* zq4 = (const float4*)(z + (size_t)(t0 + et) * DIM + eq * 16);
        float4* o4 = (float4*)(out + (size_t)(t0 + et) * DIM + eq * 16);
#pragma unroll
        for (int jj = 0; jj < 4; ++jj) {
#pragma clang fp contract(off)
            float4 cc = cq[jj];
            float4 zz = zq4[jj];
            float d0 = cc.x - zz.x, d1 = cc.y - zz.y;
            float d2 = cc.z - zz.z, d3 = cc.w - zz.w;
            float4 o;
            o.x = zz.x + d0; o.y = zz.y + d1;
            o.z = zz.z + d2; o.w = zz.w + d3;
            o4[jj] = o;
            loss_t = __fmaf_rn(d0, d0, loss_t);
            loss_t = __fmaf_rn(d1, d1, loss_t);
            loss_t = __fmaf_rn(d2, d2, loss_t);
            loss_t = __fmaf_rn(d3, d3, loss_t);
        }
        if (eq == 0) out[OUT_IDX_OFF + t0 + et] = (float)B;
    }
#pragma unroll
    for (int off = 32; off > 0; off >>= 1)
        loss_t += __shfl_down(loss_t, off);
    if (lane == 0) atomicAdd(loss_sum, (double)loss_t);
}

__device__ __forceinline__ unsigned long long shfl_down_u64(unsigned long long v, int off) {
    unsigned int lo = (unsigned int)v, hi = (unsigned int)(v >> 32);
    lo = __shfl_down(lo, off);
    hi = __shfl_down(hi, off);
    return ((unsigned long long)hi << 32) | lo;
}

// ---------------------------------------------------------------------------
// Exact numpy-bitwise pass, v3: CODE-STATIONARY. Block = one 256-code quarter
// (one code row per lane, in VGPRs, loaded once); 64 flagged tokens staged in
// LDS (pad-68 rows; main-loop reads are wave-broadcast = conflict-free).
// d packed as (bits<<10)|k -> atomicMin gives global argmin with numpy
// first-occurrence tie-breaking (d ~ 64 > 0, so f32 bits are monotone).
// Arithmetic op order identical to the round-2/5-verified bitwise scheme.
// ---------------------------------------------------------------------------
__global__ __launch_bounds__(256) void vq_exact_min(
    const float* __restrict__ z, const float* __restrict__ cb,
    const float* __restrict__ bnorm,
    const unsigned int* __restrict__ flag_count,
    const int* __restrict__ flag_list,
    unsigned long long* __restrict__ packed_min, unsigned int flag_cap) {
    __shared__ float zsh[64 * 68];
    __shared__ float szs[64];

    const int tid = threadIdx.x;
    const int w = tid >> 6;
    const int lane = tid & 63;
    unsigned int count = *flag_count;
    if (count > flag_cap) count = flag_cap;
    const unsigned int ngroups = (count + 63) >> 6;

    const int q = blockIdx.x & 3;
    const unsigned int g = blockIdx.x >> 2;          // 0..127; ngroups <= 128
    if (g >= ngroups) return;

    const int k = q * 256 + w * 64 + lane;           // this lane's code

    // code row into registers (once) + its bnorm
    float row[DIM];
    {
        const float4* c4 = (const float4*)(cb + (size_t)k * DIM);
#pragma unroll
        for (int j = 0; j < 16; ++j) {
            float4 v = c4[j];
            row[4 * j + 0] = v.x; row[4 * j + 1] = v.y;
            row[4 * j + 2] = v.z; row[4 * j + 3] = v.w;
        }
    }
    const float bnk = bnorm[k];

    // stage this group's 64 tokens into LDS (coalesced-ish, once)
    {
        const int i = tid >> 2, part = tid & 3;
        const unsigned int li = g * 64 + i;
        if (li < count) {
            const int t = flag_list[li];
            const float4* zp = (const float4*)(z + (size_t)t * DIM + part * 16);
            float4* dst = (float4*)(zsh + i * 68 + part * 16);
#pragma unroll
            for (int e = 0; e < 4; ++e) dst[e] = zp[e];
        }
    }
    __syncthreads();
    if (tid < 64) {
        // np-bitwise ||z||^2 per token (same values, same op order)
        szs[tid] = np_sumsq64(zsh + tid * 68);
    }
    __syncthreads();

    for (int tt = 0; tt < 64; ++tt) {
        const unsigned int li = g * 64 + tt;
        const float* zp = zsh + tt * 68;             // wave-uniform -> broadcast
        float l16[16];
#pragma unroll
        for (int g2 = 0; g2 < 4; ++g2) {
            float4 v0 = ((const float4*)(zp + 4 * g2))[0];
            float4 v1 = ((const float4*)(zp + 16 + 4 * g2))[0];
            float4 v2 = ((const float4*)(zp + 32 + 4 * g2))[0];
            float4 v3 = ((const float4*)(zp + 48 + 4 * g2))[0];
            float a0[4] = {v0.x, v0.y, v0.z, v0.w};
            float a1[4] = {v1.x, v1.y, v1.z, v1.w};
            float a2[4] = {v2.x, v2.y, v2.z, v2.w};
            float a3[4] = {v3.x, v3.y, v3.z, v3.w};
#pragma unroll
            for (int e = 0; e < 4; ++e) {
#pragma clang fp contract(off)
                int jj = 4 * g2 + e;
                float acc = a3[e] * row[48 + jj];
                acc = __fmaf_rn(a2[e], row[32 + jj], acc);
                acc = __fmaf_rn(a1[e], row[16 + jj], acc);
                acc = __fmaf_rn(a0[e], row[jj],      acc);
                l16[jj] = acc;
            }
        }
        float e_np;
        {
#pragma clang fp contract(off)
#pragma unroll
            for (int jj = 0; jj < 8; ++jj) l16[jj] = l16[jj] + l16[jj + 8];
#pragma unroll
            for (int jj = 0; jj < 4; ++jj) l16[jj] = l16[jj] + l16[jj + 4];
            l16[0] = l16[0] + l16[2];
            l16[1] = l16[1] + l16[3];
            e_np = l16[0] + l16[1];
        }
        float dd;
        {
#pragma clang fp contract(off)
            float t1 = szs[tt] + bnk;
            float mm = 2.0f * e_np;
            dd = t1 - mm;
        }
        unsigned long long pk =
            ((unsigned long long)__float_as_uint(dd) << 10) | (unsigned int)k;
#pragma unroll
        for (int off = 32; off > 0; off >>= 1) {
            unsigned long long o = shfl_down_u64(pk, off);
            pk = (o < pk) ? o : pk;
        }
        if (lane == 0 && li < count)
            atomicMin(&packed_min[li], pk);
    }
}

// write outputs for flagged tokens from the argmin table
__global__ __launch_bounds__(256) void vq_finish(
    const float* __restrict__ z, const float* __restrict__ cb,
    float* __restrict__ out, const unsigned int* __restrict__ flag_count,
    const int* __restrict__ flag_list,
    const unsigned long long* __restrict__ packed_min,
    double* __restrict__ loss_sum, unsigned int flag_cap) {
    const int lane = threadIdx.x & 63;
    unsigned int count = *flag_count;
    if (count > flag_cap) count = flag_cap;
    const unsigned int gw = blockIdx.x * 4 + (threadIdx.x >> 6);
    const unsigned int NW = gridDim.x * 4;

    for (unsigned int li = gw; li < count; li += NW) {
        const int t = flag_list[li];
        const int best = (int)(packed_min[li] & 1023ull);
        const float zl = z[(size_t)t * DIM + lane];
        const float zq = cb[(size_t)best * DIM + lane];
        float d, o;
        {
#pragma clang fp contract(off)
            d = zq - zl;
            o = zl + d;
        }
        out[(size_t)t * DIM + lane] = o;
        float l2 = d * d;
#pragma unroll
        for (int off = 32; off > 0; off >>= 1)
            l2 += __shfl_down(l2, off);
        if (lane == 0) {
            out[OUT_IDX_OFF + t] = (float)best;
            atomicAdd(loss_sum, (double)l2);
        }
    }
}

__global__ void vq_loss_final(const double* __restrict__ loss_sum,
                              float* __restrict__ out) {
    out[OUT_LOSS_OFF] = (float)(2.0 * (*loss_sum) / (double)((size_t)TOKENS * DIM));
}

extern "C" void kernel_launch(void* const* d_in, const int* in_sizes, int n_in,
                              void* d_out, int out_size, void* d_ws, size_t ws_size,
                              hipStream_t stream) {
    const float* z  = (const float*)d_in[0];   // [8,8192,64] f32
    const float* cb = (const float*)d_in[1];   // [1024,64] f32
    float* out = (float*)d_out;

    char* ws = (char*)d_ws;
    double* loss_sum = (double*)(ws + WS_LOSS);
    unsigned int* flag_count = (unsigned int*)(ws + WS_FLAGC);
    float* bnorm = (float*)(ws + WS_BNORM);
    float* bnf = (float*)(ws + WS_BNF);
    unsigned short* chi = (unsigned short*)(ws + WS_CHI);
    unsigned short* clo = (unsigned short*)(ws + WS_CLO);
    unsigned long long* packed = (unsigned long long*)(ws + WS_PACKED);
    int* flag_list = (int*)(ws + WS_FLAGS);

    unsigned int cap = 0;
    if (ws_size > WS_FLAGS + 4) {
        size_t c = (ws_size - WS_FLAGS) / 4;
        cap = (c > FLAG_CAP) ? FLAG_CAP : (unsigned int)c;
    }

    hipMemsetAsync(ws, 0, 16, stream);                      // loss + flag_count
    hipMemsetAsync(ws + WS_PACKED, 0xFF, FLAG_CAP * 8, stream);
    vq_bnorm<<<dim3(NCODE / 256), dim3(256), 0, stream>>>(cb, bnorm);
    vq_prep<<<dim3(256), dim3(256), 0, stream>>>(cb, bnorm, chi, clo, bnf);
    vq_fast<<<dim3(TOKENS / 64), dim3(256), 0, stream>>>(
        z, cb, chi, clo, bnf, out, flag_count, flag_list, loss_sum, cap);
    vq_exact_min<<<dim3(512), dim3(256), 0, stream>>>(
        z, cb, bnorm, flag_count, flag_list, packed, cap);
    vq_finish<<<dim3(128), dim3(256), 0, stream>>>(
        z, cb, out, flag_count, flag_list, packed, loss_sum, cap);
    vq_loss_final<<<dim3(1), dim3(1), 0, stream>>>(loss_sum, out);
}

// Round 7
// 267.409 us; speedup vs baseline: 2.0044x; 1.0360x over previous
//
#include <hip/hip_runtime.h>

#define TOKENS 65536
#define DIM 64
#define NCODE 1024
#define MARGIN 2.5e-4f
#define FLAG_CAP 8192

#define OUT_IDX_OFF ((size_t)TOKENS * DIM)          // 4194304
#define OUT_LOSS_OFF (OUT_IDX_OFF + TOKENS)         // 4259840

// ws layout (bytes):
#define WS_LOSS   0        // double
#define WS_FLAGC  8        // uint
#define WS_BNORM  16       // f32[1024]      -> 4112
#define WS_BNF    4224     // f32[16384]     -> 69760  (bnorm in C-frag layout)
#define WS_CHI    69760    // ushort[65536]  -> 200832 (codebook -2c hi, A-frag)
#define WS_CLO    200832   // ushort[65536]  -> 331904 (codebook -2c lo)
#define WS_PACKED 331904   // u64[8192]      -> 397440 (per-flagged argmin)
#define WS_FLAGS  397440   // int[8192]      -> 430208

typedef __attribute__((ext_vector_type(8))) short short8;
typedef __attribute__((ext_vector_type(4))) float f32x4;

// ---------------------------------------------------------------------------
// numpy-bitwise f32 sum-of-squares — VERIFIED absmax=0 (round 2). Do not touch.
// ---------------------------------------------------------------------------
__device__ __forceinline__ float np_sumsq64(const float* __restrict__ x) {
#pragma clang fp contract(off)
    float r[8];
#pragma unroll
    for (int j = 0; j < 8; ++j) r[j] = x[j] * x[j];
#pragma unroll
    for (int i = 8; i < 64; i += 8) {
#pragma unroll
        for (int j = 0; j < 8; ++j) {
            float sq = x[i + j] * x[i + j];
            r[j] = r[j] + sq;
        }
    }
    return ((r[0] + r[1]) + (r[2] + r[3])) + ((r[4] + r[5]) + (r[6] + r[7]));
}

// ---------------------------------------------------------------------------
// Prep (fused bnorm): codebook -> bf16 hi/lo A-frags of (-2*C), bnorm table,
// bnf in C-frag layout (bnf entries compute their own sumsq -> no cross-block
// dependency). A-frag/bnf formulas verified absmax=0 rounds 4-6.
// ---------------------------------------------------------------------------
__global__ __launch_bounds__(256) void vq_prep(
    const float* __restrict__ cb, unsigned short* __restrict__ chi,
    unsigned short* __restrict__ clo, float* __restrict__ bnorm,
    float* __restrict__ bnf) {
    int tid = blockIdx.x * 256 + threadIdx.x;   // 0..65535
    int j = tid & 7;
    int L = (tid >> 3) & 63;
    int cs = tid >> 9;          // 0..127
    int s = cs & 1, c = cs >> 1;
    int code = c * 16 + (L & 15);
    int d = s * 32 + (L >> 4) * 8 + j;
    float v = -2.0f * cb[(size_t)code * DIM + d];
    unsigned int b = __float_as_uint(v);
    chi[tid] = (unsigned short)(b >> 16);                       // truncation split
    float hf = __uint_as_float(b & 0xFFFF0000u);
    float lo;
    {
#pragma clang fp contract(off)
        lo = v - hf;                                            // exact in f32
    }
    clo[tid] = (unsigned short)(__float_as_uint(lo) >> 16);

    if (tid < NCODE) bnorm[tid] = np_sumsq64(cb + (size_t)tid * DIM);
    if (tid < 16384) {
        int i = tid & 3, lane = (tid >> 2) & 63, cc = tid >> 8;
        int code2 = cc * 16 + ((lane >> 4) * 4) + i;
        bnf[tid] = np_sumsq64(cb + (size_t)code2 * DIM);
    }
}

__device__ __forceinline__ void top2_merge(float& a1, float& a2, int& ai,
                                           float b1, float b2, int bi) {
    float n1 = fminf(a1, b1);
    float n2 = fminf(fmaxf(a1, b1), fminf(a2, b2));
    ai = (b1 < a1) ? bi : ai;   // ties keep a (exact ties get flagged anyway)
    a1 = n1; a2 = n2;
}

// ---------------------------------------------------------------------------
// Fast screen, v3. Block = 4 waves x 32 tokens = 128 tokens; each wave scans
// ALL 1024 codes (64 chunks of 16) for its 32 tokens (2 MFMA col-tiles).
// All 4 waves stream the SAME A-frag sequence -> 4x L1 reuse. Live VGPRs
// ~117 < 128 cap from (256,4) -> no spills (round-6 lesson: WRITE_SIZE is
// the spill detector). MFMA chain + numerics identical to verified rounds.
// ---------------------------------------------------------------------------
__global__ __launch_bounds__(256, 4) void vq_fast(
    const float* __restrict__ z, const float* __restrict__ cb,
    const unsigned short* __restrict__ cfrag_hi,
    const unsigned short* __restrict__ cfrag_lo,
    const float* __restrict__ bnorm_frag, float* __restrict__ out,
    unsigned int* __restrict__ flag_count, int* __restrict__ flag_list,
    double* __restrict__ loss_sum, unsigned int flag_cap) {
    __shared__ int s_best[128];
    __shared__ int s_flag[128];

    const int tid = threadIdx.x;
    const int lane = tid & 63;
    const int w = tid >> 6;
    const int t0 = blockIdx.x * 128;
    const int tw = t0 + w * 32;              // this wave's 32 tokens
    const int col = lane & 15;
    const int quad = lane >> 4;

    // token B-fragments (bf16 hi/lo), 2 tiles x 2 K-steps, in registers
    short8 zhi[2][2], zlo[2][2];
#pragma unroll
    for (int tt = 0; tt < 2; ++tt) {
#pragma unroll
        for (int s = 0; s < 2; ++s) {
            const float* zp = z + (size_t)(tw + tt * 16 + col) * DIM + s * 32 + quad * 8;
            float4 f0 = ((const float4*)zp)[0];
            float4 f1 = ((const float4*)zp)[1];
            float f[8] = {f0.x, f0.y, f0.z, f0.w, f1.x, f1.y, f1.z, f1.w};
            short8 h, l;
#pragma unroll
            for (int j = 0; j < 8; ++j) {
                unsigned int b = __float_as_uint(f[j]);
                h[j] = (short)(b >> 16);
                float hf = __uint_as_float(b & 0xFFFF0000u);
                float lo;
                {
#pragma clang fp contract(off)
                    lo = f[j] - hf;
                }
                l[j] = (short)(__float_as_uint(lo) >> 16);
            }
            zhi[tt][s] = h; zlo[tt][s] = l;
        }
    }

    float m1[2] = {3.0e38f, 3.0e38f};
    float m2[2] = {3.0e38f, 3.0e38f};
    int bi[2] = {0, 0};

    const short8* CH = (const short8*)cfrag_hi;
    const short8* CL = (const short8*)cfrag_lo;
    const f32x4* BN = (const f32x4*)bnorm_frag;
    const int koff = quad * 4;

    short8 ch0 = CH[0 * 64 + lane];
    short8 ch1 = CH[1 * 64 + lane];
    short8 cl0 = CL[0 * 64 + lane];
    short8 cl1 = CL[1 * 64 + lane];
    f32x4 bn = BN[lane];

    for (int c = 0; c < 64; ++c) {
        const int cn = (c < 63) ? c + 1 : c;   // last iter: redundant reload
        short8 nh0 = CH[(cn * 2 + 0) * 64 + lane];
        short8 nh1 = CH[(cn * 2 + 1) * 64 + lane];
        short8 nl0 = CL[(cn * 2 + 0) * 64 + lane];
        short8 nl1 = CL[(cn * 2 + 1) * 64 + lane];
        f32x4 nbn = BN[cn * 64 + lane];

        const int cbase = c * 16 + koff;
#pragma unroll
        for (int tt = 0; tt < 2; ++tt) {
            f32x4 acc = bn;
            acc = __builtin_amdgcn_mfma_f32_16x16x32_bf16(ch0, zhi[tt][0], acc, 0, 0, 0);
            acc = __builtin_amdgcn_mfma_f32_16x16x32_bf16(cl0, zhi[tt][0], acc, 0, 0, 0);
            acc = __builtin_amdgcn_mfma_f32_16x16x32_bf16(ch0, zlo[tt][0], acc, 0, 0, 0);
            acc = __builtin_amdgcn_mfma_f32_16x16x32_bf16(ch1, zhi[tt][1], acc, 0, 0, 0);
            acc = __builtin_amdgcn_mfma_f32_16x16x32_bf16(cl1, zhi[tt][1], acc, 0, 0, 0);
            acc = __builtin_amdgcn_mfma_f32_16x16x32_bf16(ch1, zlo[tt][1], acc, 0, 0, 0);
#pragma unroll
            for (int i = 0; i < 4; ++i) {
                float u = acc[i];
                float om1 = m1[tt];
                bool lt = u < om1;
                float fm = fminf(m2[tt], u);
                m2[tt] = lt ? om1 : fm;
                m1[tt] = lt ? u : om1;
                bi[tt] = lt ? (cbase + i) : bi[tt];
            }
        }
        ch0 = nh0; ch1 = nh1; cl0 = nl0; cl1 = nl1; bn = nbn;
    }

    // in-wave quad merge (lanes l, l^16, l^32, l^48 share a token column)
#pragma unroll
    for (int tt = 0; tt < 2; ++tt) {
        float a1 = m1[tt], a2 = m2[tt];
        int ai = bi[tt];
        {
            float o1 = __shfl_xor(a1, 16); float o2 = __shfl_xor(a2, 16);
            int oi = __shfl_xor(ai, 16);
            top2_merge(a1, a2, ai, o1, o2, oi);
        }
        {
            float o1 = __shfl_xor(a1, 32); float o2 = __shfl_xor(a2, 32);
            int oi = __shfl_xor(ai, 32);
            top2_merge(a1, a2, ai, o1, o2, oi);
        }
        if (quad == 0) {
            const int slot = w * 32 + tt * 16 + col;   // token slot in block
            int fl = (a2 - a1) < MARGIN;
            if (fl) {
                unsigned int pos = atomicAdd(flag_count, 1u);
                if (pos >= flag_cap) fl = 0;
                else flag_list[pos] = t0 + slot;
            }
            s_best[slot] = ai;
            s_flag[slot] = fl;
        }
    }
    __syncthreads();

    // epilogue: 2 threads per token (32 floats each); flagged tokens deferred
    const int et = tid >> 1, h = tid & 1;
    float loss_t = 0.0f;
    if (!s_flag[et]) {
        const int B = s_best[et];
        const float4* cq  = (const float4*)(cb + (size_t)B * DIM + h * 32);
        const float4* zq4 = (const float4*)(z + (size_t)(t0 + et) * DIM + h * 32);
        float4* o4 = (float4*)(out + (size_t)(t0 + et) * DIM + h * 32);
#pragma unroll
        for (int jj = 0; jj < 8; ++jj) {
#pragma clang fp contract(off)
            float4 cc = cq[jj];
            float4 zz = zq4[jj];
            float d0 = cc.x - zz.x, d1 = cc.y - zz.y;
            float d2 = cc.z - zz.z, d3 = cc.w - zz.w;
            float4 o;
            o.x = zz.x + d0; o.y = zz.y + d1;
            o.z = zz.z + d2; o.w = zz.w + d3;
            o4[jj] = o;
            loss_t = __fmaf_rn(d0, d0, loss_t);
            loss_t = __fmaf_rn(d1, d1, loss_t);
            loss_t = __fmaf_rn(d2, d2, loss_t);
            loss_t = __fmaf_rn(d3, d3, loss_t);
        }
        if (h == 0) out[OUT_IDX_OFF + t0 + et] = (float)B;
    }
#pragma unroll
    for (int off = 32; off > 0; off >>= 1)
        loss_t += __shfl_down(loss_t, off);
    if (lane == 0) atomicAdd(loss_sum, (double)loss_t);
}

__device__ __forceinline__ unsigned long long shfl_down_u64(unsigned long long v, int off) {
    unsigned int lo = (unsigned int)v, hi = (unsigned int)(v >> 32);
    lo = __shfl_down(lo, off);
    hi = __shfl_down(hi, off);
    return ((unsigned long long)hi << 32) | lo;
}

// ---------------------------------------------------------------------------
// Exact numpy-bitwise pass (code-stationary) — verified absmax=0 round 6.
// ---------------------------------------------------------------------------
__global__ __launch_bounds__(256) void vq_exact_min(
    const float* __restrict__ z, const float* __restrict__ cb,
    const float* __restrict__ bnorm,
    const unsigned int* __restrict__ flag_count,
    const int* __restrict__ flag_list,
    unsigned long long* __restrict__ packed_min, unsigned int flag_cap) {
    __shared__ float zsh[64 * 68];
    __shared__ float szs[64];

    const int tid = threadIdx.x;
    const int w = tid >> 6;
    const int lane = tid & 63;
    unsigned int count = *flag_count;
    if (count > flag_cap) count = flag_cap;
    const unsigned int ngroups = (count + 63) >> 6;

    const int q = blockIdx.x & 3;
    const unsigned int g = blockIdx.x >> 2;          // 0..127; ngroups <= 128
    if (g >= ngroups) return;

    const int k = q * 256 + w * 64 + lane;           // this lane's code

    float row[DIM];
    {
        const float4* c4 = (const float4*)(cb + (size_t)k * DIM);
#pragma unroll
        for (int j = 0; j < 16; ++j) {
            float4 v = c4[j];
            row[4 * j + 0] = v.x; row[4 * j + 1] = v.y;
            row[4 * j + 2] = v.z; row[4 * j + 3] = v.w;
        }
    }
    const float bnk = bnorm[k];

    {
        const int i = tid >> 2, part = tid & 3;
        const unsigned int li = g * 64 + i;
        if (li < count) {
            const int t = flag_list[li];
            const float4* zp = (const float4*)(z + (size_t)t * DIM + part * 16);
            float4* dst = (float4*)(zsh + i * 68 + part * 16);
#pragma unroll
            for (int e = 0; e < 4; ++e) dst[e] = zp[e];
        }
    }
    __syncthreads();
    if (tid < 64) szs[tid] = np_sumsq64(zsh + tid * 68);
    __syncthreads();

    for (int tt = 0; tt < 64; ++tt) {
        const unsigned int li = g * 64 + tt;
        const float* zp = zsh + tt * 68;             // wave-uniform -> broadcast
        float l16[16];
#pragma unroll
        for (int g2 = 0; g2 < 4; ++g2) {
            float4 v0 = ((const float4*)(zp + 4 * g2))[0];
            float4 v1 = ((const float4*)(zp + 16 + 4 * g2))[0];
            float4 v2 = ((const float4*)(zp + 32 + 4 * g2))[0];
            float4 v3 = ((const float4*)(zp + 48 + 4 * g2))[0];
            float a0[4] = {v0.x, v0.y, v0.z, v0.w};
            float a1[4] = {v1.x, v1.y, v1.z, v1.w};
            float a2[4] = {v2.x, v2.y, v2.z, v2.w};
            float a3[4] = {v3.x, v3.y, v3.z, v3.w};
#pragma unroll
            for (int e = 0; e < 4; ++e) {
#pragma clang fp contract(off)
                int jj = 4 * g2 + e;
                float acc = a3[e] * row[48 + jj];
                acc = __fmaf_rn(a2[e], row[32 + jj], acc);
                acc = __fmaf_rn(a1[e], row[16 + jj], acc);
                acc = __fmaf_rn(a0[e], row[jj],      acc);
                l16[jj] = acc;
            }
        }
        float e_np;
        {
#pragma clang fp contract(off)
#pragma unroll
            for (int jj = 0; jj < 8; ++jj) l16[jj] = l16[jj] + l16[jj + 8];
#pragma unroll
            for (int jj = 0; jj < 4; ++jj) l16[jj] = l16[jj] + l16[jj + 4];
            l16[0] = l16[0] + l16[2];
            l16[1] = l16[1] + l16[3];
            e_np = l16[0] + l16[1];
        }
        float dd;
        {
#pragma clang fp contract(off)
            float t1 = szs[tt] + bnk;
            float mm = 2.0f * e_np;
            dd = t1 - mm;
        }
        unsigned long long pk =
            ((unsigned long long)__float_as_uint(dd) << 10) | (unsigned int)k;
#pragma unroll
        for (int off = 32; off > 0; off >>= 1) {
            unsigned long long o = shfl_down_u64(pk, off);
            pk = (o < pk) ? o : pk;
        }
        if (lane == 0 && li < count)
            atomicMin(&packed_min[li], pk);
    }
}

__global__ __launch_bounds__(256) void vq_finish(
    const float* __restrict__ z, const float* __restrict__ cb,
    float* __restrict__ out, const unsigned int* __restrict__ flag_count,
    const int* __restrict__ flag_list,
    const unsigned long long* __restrict__ packed_min,
    double* __restrict__ loss_sum, unsigned int flag_cap) {
    const int lane = threadIdx.x & 63;
    unsigned int count = *flag_count;
    if (count > flag_cap) count = flag_cap;
    const unsigned int gw = blockIdx.x * 4 + (threadIdx.x >> 6);
    const unsigned int NW = gridDim.x * 4;

    for (unsigned int li = gw; li < count; li += NW) {
        const int t = flag_list[li];
        const int best = (int)(packed_min[li] & 1023ull);
        const float zl = z[(size_t)t * DIM + lane];
        const float zq = cb[(size_t)best * DIM + lane];
        float d, o;
        {
#pragma clang fp contract(off)
            d = zq - zl;
            o = zl + d;
        }
        out[(size_t)t * DIM + lane] = o;
        float l2 = d * d;
#pragma unroll
        for (int off = 32; off > 0; off >>= 1)
            l2 += __shfl_down(l2, off);
        if (lane == 0) {
            out[OUT_IDX_OFF + t] = (float)best;
            atomicAdd(loss_sum, (double)l2);
        }
    }
}

__global__ void vq_loss_final(const double* __restrict__ loss_sum,
                              float* __restrict__ out) {
    out[OUT_LOSS_OFF] = (float)(2.0 * (*loss_sum) / (double)((size_t)TOKENS * DIM));
}

extern "C" void kernel_launch(void* const* d_in, const int* in_sizes, int n_in,
                              void* d_out, int out_size, void* d_ws, size_t ws_size,
                              hipStream_t stream) {
    const float* z  = (const float*)d_in[0];   // [8,8192,64] f32
    const float* cb = (const float*)d_in[1];   // [1024,64] f32
    float* out = (float*)d_out;

    char* ws = (char*)d_ws;
    double* loss_sum = (double*)(ws + WS_LOSS);
    unsigned int* flag_count = (unsigned int*)(ws + WS_FLAGC);
    float* bnorm = (float*)(ws + WS_BNORM);
    float* bnf = (float*)(ws + WS_BNF);
    unsigned short* chi = (unsigned short*)(ws + WS_CHI);
    unsigned short* clo = (unsigned short*)(ws + WS_CLO);
    unsigned long long* packed = (unsigned long long*)(ws + WS_PACKED);
    int* flag_list = (int*)(ws + WS_FLAGS);

    unsigned int cap = 0;
    if (ws_size > WS_FLAGS + 4) {
        size_t c = (ws_size - WS_FLAGS) / 4;
        cap = (c > FLAG_CAP) ? FLAG_CAP : (unsigned int)c;
    }

    hipMemsetAsync(ws, 0, 16, stream);                      // loss + flag_count
    hipMemsetAsync(ws + WS_PACKED, 0xFF, FLAG_CAP * 8, stream);
    vq_prep<<<dim3(256), dim3(256), 0, stream>>>(cb, chi, clo, bnorm, bnf);
    vq_fast<<<dim3(TOKENS / 128), dim3(256), 0, stream>>>(
        z, cb, chi, clo, bnf, out, flag_count, flag_list, loss_sum, cap);
    vq_exact_min<<<dim3(512), dim3(256), 0, stream>>>(
        z, cb, bnorm, flag_count, flag_list, packed, cap);
    vq_finish<<<dim3(128), dim3(256), 0, stream>>>(
        z, cb, out, flag_count, flag_list, packed, loss_sum, cap);
    vq_loss_final<<<dim3(1), dim3(1), 0, stream>>>(loss_sum, out);
}